// Round 7
// baseline (433.984 us; speedup 1.0000x reference)
//
#include <hip/hip_runtime.h>

#define NBATCH 8
#define NN     207
#define DHID   256
#define LL     2484      // 12*207
#define LLP    2496      // padded to multiple of 32
#define RT     32        // rows per block in score & pv kernels
#define TILES  78        // LLP/32
#define LNEPS  1e-5f

typedef __attribute__((ext_vector_type(8)))  short bf16x8;
typedef __attribute__((ext_vector_type(4)))  unsigned u32x4;
typedef __attribute__((ext_vector_type(16))) float f32x16;

__device__ __forceinline__ short f2bf(float f) {
    unsigned u = __float_as_uint(f);
    unsigned r = (u + 0x7FFFu + ((u >> 16) & 1u)) >> 16;
    return (short)r;
}
__device__ __forceinline__ unsigned cvt_pk_bf16(float lo, float hi) {
    unsigned r;
    asm("v_cvt_pk_bf16_f32 %0, %1, %2" : "=v"(r) : "v"(lo), "v"(hi));
    return r;
}
__device__ __forceinline__ void pl32swap(unsigned& a, unsigned& b) {
    asm("v_permlane32_swap_b32 %0, %1" : "+v"(a), "+v"(b));
}

// ---------------- Kernel 1: LayerNorm + Q/K projections ----------------
__global__ __launch_bounds__(256) void k_lnproj(
    const float* __restrict__ x, const float* __restrict__ Wq, const float* __restrict__ bq,
    const float* __restrict__ Wk, const float* __restrict__ bk,
    const float* __restrict__ gamma, const float* __restrict__ beta,
    float* __restrict__ Xn, float* __restrict__ Qb, short* __restrict__ Kbf)
{
    __shared__ float xrow[4][64];
    int w = threadIdx.x >> 6, lane = threadIdx.x & 63;
    size_t row = (size_t)blockIdx.x * 4 + w;
    float xv = x[row * 64 + lane];
    float m = xv;
    #pragma unroll
    for (int o = 32; o; o >>= 1) m += __shfl_xor(m, o, 64);
    m *= (1.0f / 64.0f);
    float dv = xv - m;
    float var = dv * dv;
    #pragma unroll
    for (int o = 32; o; o >>= 1) var += __shfl_xor(var, o, 64);
    var *= (1.0f / 64.0f);
    float xg = dv * (1.0f / sqrtf(var + LNEPS)) * gamma[lane] + beta[lane];
    Xn[row * 64 + lane] = xg;
    xrow[w][lane] = xg;
    __syncthreads();
    float q = bq[lane], k = bk[lane];
    #pragma unroll 8
    for (int e = 0; e < 64; e++) {
        float xe = xrow[w][e];
        q += xe * Wq[e * 64 + lane];
        k += xe * Wk[e * 64 + lane];
    }
    int br = (int)(row / LL);
    int jl = (int)(row - (size_t)br * LL);
    Qb[((size_t)br * LLP + jl) * 64 + lane] = q;
    Kbf[((size_t)br * LLP + jl) * 64 + lane] = f2bf(k);
}

// ---------------- Kernel 1b: transpose Xn -> bf16 X^T, zero all pads ----------------
__global__ __launch_bounds__(256) void k_prep(
    const float* __restrict__ Xn, short* __restrict__ XbfT,
    short* __restrict__ Kbf, float* __restrict__ Qb)
{
    __shared__ float tile[64][65];
    int bb = blockIdx.x & 7;
    int jt = blockIdx.x >> 3;          // 0..38
    int j0 = jt * 64;
    for (int i = threadIdx.x; i < 4096; i += 256) {
        int jl = i >> 6, d = i & 63;
        int j = j0 + jl;
        tile[jl][d] = (j < LL) ? Xn[((size_t)bb * LL + j) * 64 + d] : 0.f;
    }
    __syncthreads();
    for (int i = threadIdx.x; i < 4096; i += 256) {
        int d = i >> 6, jl = i & 63;
        XbfT[((size_t)bb * 64 + d) * LLP + j0 + jl] = f2bf(tile[jl][d]);
    }
    if (jt == 38) {
        for (int i = threadIdx.x; i < (LLP - LL) * 64; i += 256) {
            int jl = i >> 6, d = i & 63;
            Kbf[((size_t)bb * LLP + LL + jl) * 64 + d] = 0;
            Qb [((size_t)bb * LLP + LL + jl) * 64 + d] = 0.f;
        }
    }
}

// --------------- suffix-scan select ---------------
__device__ __forceinline__ int scan_select(const unsigned* __restrict__ h, int lane, unsigned& kr)
{
    unsigned c0 = h[lane * 4 + 0];
    unsigned c1 = h[lane * 4 + 1];
    unsigned c2 = h[lane * 4 + 2];
    unsigned c3 = h[lane * 4 + 3];
    unsigned S = c0 + c1 + c2 + c3;
    unsigned T = S;
    #pragma unroll
    for (int off = 1; off < 64; off <<= 1) {
        unsigned t = __shfl_down(T, off, 64);
        T += (lane + off < 64) ? t : 0u;
    }
    unsigned Tn = T - S;
    unsigned sfx3 = c3 + Tn, sfx2 = c2 + sfx3, sfx1 = c1 + sfx2, sfx0 = c0 + sfx1;
    int hit = -1; unsigned nk = 0u;
    if (sfx3 >= kr && Tn   < kr) { hit = lane * 4 + 3; nk = kr - Tn; }
    if (sfx2 >= kr && sfx3 < kr) { hit = lane * 4 + 2; nk = kr - sfx3; }
    if (sfx1 >= kr && sfx2 < kr) { hit = lane * 4 + 1; nk = kr - sfx2; }
    if (sfx0 >= kr && sfx1 < kr) { hit = lane * 4 + 0; nk = kr - sfx1; }
    unsigned long long mask = __ballot(hit >= 0);
    int src = __ffsll((unsigned long long)mask) - 1;
    int bin = __shfl(hit, src, 64);
    kr = (unsigned)__shfl((int)nk, src, 64);
    return bin;
}

// ---------------- Kernel 2a: MFMA scores (2 sweeps, recompute) -> top-k threshold ----------------
__global__ __launch_bounds__(256, 4) void k_score(
    const float* __restrict__ Qb, const short* __restrict__ Kbf,
    const float* __restrict__ stg, const int* __restrict__ topk_p,
    unsigned* __restrict__ TG)
{
    __shared__ unsigned hist[RT * 256];     // 32 KB
    __shared__ int gmax_w[4][RT];
    __shared__ int gmax_lds[RT];
    __shared__ int b0_lds[RT];
    __shared__ int kr_lds[RT];
    __shared__ int thr_lds[RT];

    int tid = threadIdx.x;
    int lane = tid & 63, wv = tid >> 6;
    int hi = lane >> 5, l31 = lane & 31;
    int b = blockIdx.x & 7;
    int tile = blockIdx.x >> 3;             // 0..77
    int row0 = tile * RT;

    for (int i = tid; i < RT * 256; i += 256) hist[i] = 0u;

    int keff;
    { int tk = *topk_p; keff = (tk < 5) ? tk * NN : tk; }

    // Q A-fragments: row = row0 + l31 (padded Qb -> always in-bounds)
    bf16x8 qf[4];
    {
        const float* qp = Qb + ((size_t)b * LLP + row0 + l31) * 64 + hi * 8;
        #pragma unroll
        for (int kk = 0; kk < 4; kk++) {
            bf16x8 f;
            #pragma unroll
            for (int e = 0; e < 8; e++) f[e] = f2bf(qp[kk * 16 + e]);
            qf[kk] = f;
        }
    }
    __syncthreads();   // hist zeros visible

    const float* stgb = stg + (size_t)b * LL * LL;

    int gmx[16];
    #pragma unroll
    for (int i = 0; i < 16; i++) gmx[i] = 0;

    int t0 = wv * 20;
    int t1 = (t0 + 20 < TILES) ? t0 + 20 : TILES;

    // ---- sweep 1: g -> hist + gmax ----
    for (int t = t0; t < t1; ++t) {
        int j0 = t * 32;
        int j = j0 + l31;
        bool jv = (j < LL);
        f32x16 c = {0.f,0.f,0.f,0.f,0.f,0.f,0.f,0.f,0.f,0.f,0.f,0.f,0.f,0.f,0.f,0.f};
        const short* kbase = Kbf + ((size_t)b * LLP + j0 + l31) * 64 + hi * 8;
        #pragma unroll
        for (int kk = 0; kk < 4; kk++) {
            bf16x8 kv = *(const bf16x8*)(kbase + kk * 16);
            c = __builtin_amdgcn_mfma_f32_32x32x16_bf16(qf[kk], kv, c, 0, 0, 0);
        }
        #pragma unroll
        for (int reg = 0; reg < 16; reg++) {
            int row = (reg & 3) + 8 * (reg >> 2) + 4 * hi;
            int grow = row0 + row;
            bool v = jv && (grow < LL);
            float sg = 1.0f / (1.0f + __expf(c[reg] * -0.125f));
            float sv = v ? sg * stgb[(size_t)grow * LL + j] : 0.f;
            int g = (int)(sv * 65536.0f); g = (g > 65535) ? 65535 : g;
            if (v) {
                atomicAdd(&hist[row * 256 + (g >> 8)], 1u);
                gmx[reg] = (g > gmx[reg]) ? g : gmx[reg];
            }
        }
    }
    #pragma unroll
    for (int reg = 0; reg < 16; reg++) {
        #pragma unroll
        for (int off = 1; off < 32; off <<= 1) {
            int o2 = __shfl_xor(gmx[reg], off, 64);
            gmx[reg] = (o2 > gmx[reg]) ? o2 : gmx[reg];
        }
    }
    if (l31 == 0) {
        #pragma unroll
        for (int reg = 0; reg < 16; reg++)
            gmax_w[wv][(reg & 3) + 8 * (reg >> 2) + 4 * hi] = gmx[reg];
    }
    __syncthreads();

    if (tid < RT) {
        int m0 = gmax_w[0][tid] > gmax_w[1][tid] ? gmax_w[0][tid] : gmax_w[1][tid];
        int m1 = gmax_w[2][tid] > gmax_w[3][tid] ? gmax_w[2][tid] : gmax_w[3][tid];
        gmax_lds[tid] = m0 > m1 ? m0 : m1;
    }

    // pass-0 scan: 8 rows per wave
    #pragma unroll 1
    for (int rr = 0; rr < 8; rr++) {
        int row = wv * 8 + rr;
        unsigned kr = (unsigned)keff;
        int bin = scan_select(&hist[row * 256], lane, kr);
        if (lane == 0) { b0_lds[row] = bin; kr_lds[row] = (int)kr; }
    }
    __syncthreads();
    for (int i = tid; i < RT * 256; i += 256) hist[i] = 0u;
    __syncthreads();

    // ---- sweep 2: recompute g (bitwise identical), refine histogram ----
    for (int t = t0; t < t1; ++t) {
        int j0 = t * 32;
        int j = j0 + l31;
        bool jv = (j < LL);
        f32x16 c = {0.f,0.f,0.f,0.f,0.f,0.f,0.f,0.f,0.f,0.f,0.f,0.f,0.f,0.f,0.f,0.f};
        const short* kbase = Kbf + ((size_t)b * LLP + j0 + l31) * 64 + hi * 8;
        #pragma unroll
        for (int kk = 0; kk < 4; kk++) {
            bf16x8 kv = *(const bf16x8*)(kbase + kk * 16);
            c = __builtin_amdgcn_mfma_f32_32x32x16_bf16(qf[kk], kv, c, 0, 0, 0);
        }
        #pragma unroll
        for (int reg = 0; reg < 16; reg++) {
            int row = (reg & 3) + 8 * (reg >> 2) + 4 * hi;
            int grow = row0 + row;
            bool v = jv && (grow < LL);
            float sg = 1.0f / (1.0f + __expf(c[reg] * -0.125f));
            float sv = v ? sg * stgb[(size_t)grow * LL + j] : 0.f;
            int g = (int)(sv * 65536.0f); g = (g > 65535) ? 65535 : g;
            if (v && (g >> 8) == b0_lds[row]) atomicAdd(&hist[row * 256 + (g & 255)], 1u);
        }
    }
    __syncthreads();
    #pragma unroll 1
    for (int rr = 0; rr < 8; rr++) {
        int row = wv * 8 + rr;
        unsigned kr = (unsigned)kr_lds[row];
        int bin = scan_select(&hist[row * 256], lane, kr);
        if (lane == 0) thr_lds[row] = b0_lds[row] * 256 + bin;
    }
    __syncthreads();

    if (tid < RT) {
        int grow = row0 + tid;
        unsigned tg = (grow < LL)
            ? (((unsigned)gmax_lds[tid] << 16) | (unsigned)(thr_lds[tid] & 0xFFFF))
            : 0xFFFFFFFFu;
        TG[(size_t)b * LLP + grow] = tg;
    }
}

// ---------------- Kernel 2b: PV with swapped-QK recompute + permlane pack ----------------
__global__ __launch_bounds__(256, 4) void k_pv(
    const float* __restrict__ Xn, const float* __restrict__ Qb,
    const short* __restrict__ Kbf, const short* __restrict__ XbfT,
    const float* __restrict__ stg, const unsigned* __restrict__ TG,
    float* __restrict__ Z)
{
    __shared__ float red_pv[4][RT][64];     // 32 KB
    __shared__ float redsum[4][RT];

    int tid = threadIdx.x;
    int lane = tid & 63, wv = tid >> 6;
    int hi = lane >> 5, l31 = lane & 31;
    int b = blockIdx.x & 7;
    int tile = blockIdx.x >> 3;
    int row0 = tile * RT;

    // B-operand: this lane's own query row (padded Qb)
    bf16x8 qf[4];
    {
        const float* qp = Qb + ((size_t)b * LLP + row0 + l31) * 64 + hi * 8;
        #pragma unroll
        for (int kk = 0; kk < 4; kk++) {
            bf16x8 f;
            #pragma unroll
            for (int e = 0; e < 8; e++) f[e] = f2bf(qp[kk * 16 + e]);
            qf[kk] = f;
        }
    }
    unsigned tg = TG[(size_t)b * LLP + row0 + l31];
    int thr = (int)(tg & 0xFFFFu);
    int gmax = (int)(tg >> 16);
    int query = row0 + l31;
    bool rv = (query < LL);
    const float* stgrow = stg + (size_t)b * LL * LL + (size_t)query * LL;
    const short* xb0 = XbfT + ((size_t)b * 64 + l31) * LLP + hi * 8;
    const short* xb1 = XbfT + ((size_t)b * 64 + 32 + l31) * LLP + hi * 8;

    f32x16 p0 = {0.f,0.f,0.f,0.f,0.f,0.f,0.f,0.f,0.f,0.f,0.f,0.f,0.f,0.f,0.f,0.f};
    f32x16 p1 = p0;
    float smr = 0.f;

    int kt0 = wv * 20;
    int kt1 = (kt0 + 20 < TILES) ? kt0 + 20 : TILES;
    for (int kt = kt0; kt < kt1; ++kt) {
        int j0 = kt * 32;
        // swapped QK^T: A = K (rows j), B = Q (cols = query) -> lane holds its row's scores
        f32x16 c = {0.f,0.f,0.f,0.f,0.f,0.f,0.f,0.f,0.f,0.f,0.f,0.f,0.f,0.f,0.f,0.f};
        const short* kbase = Kbf + ((size_t)b * LLP + j0 + l31) * 64 + hi * 8;
        #pragma unroll
        for (int kk = 0; kk < 4; kk++) {
            bf16x8 kv = *(const bf16x8*)(kbase + kk * 16);
            c = __builtin_amdgcn_mfma_f32_32x32x16_bf16(kv, qf[kk], c, 0, 0, 0);
        }
        #pragma unroll
        for (int grp = 0; grp < 2; grp++) {
            int jb1 = j0 + grp * 16 + 4 * hi;
            int jb2 = jb1 + 8;
            float4 s1 = (rv && jb1 + 3 < LL) ? *(const float4*)(stgrow + jb1)
                                             : make_float4(0.f, 0.f, 0.f, 0.f);
            float4 s2 = (rv && jb2 + 3 < LL) ? *(const float4*)(stgrow + jb2)
                                             : make_float4(0.f, 0.f, 0.f, 0.f);
            float sv[8] = {s1.x, s1.y, s1.z, s1.w, s2.x, s2.y, s2.z, s2.w};
            float ev[8];
            #pragma unroll
            for (int r = 0; r < 8; r++) {
                float sg = 1.0f / (1.0f + __expf(c[grp * 8 + r] * -0.125f));
                float s = sg * sv[r];
                int g = (int)(s * 65536.0f); g = (g > 65535) ? 65535 : g;
                bool keep = (g > thr) || (g == gmax && sv[r] > 0.f);
                ev[r] = keep ? __expf((float)(g - gmax) * (1.0f / 65536.0f)) : 0.f;
                smr += ev[r];
            }
            unsigned a0 = cvt_pk_bf16(ev[0], ev[1]);
            unsigned a1 = cvt_pk_bf16(ev[2], ev[3]);
            unsigned b0 = cvt_pk_bf16(ev[4], ev[5]);
            unsigned b1 = cvt_pk_bf16(ev[6], ev[7]);
            pl32swap(a0, b0);   // a0 -> (hi0: j 0,1 | hi1: j 8,9) ; b0 -> (hi0: j 4,5 | hi1: j 12,13)
            pl32swap(a1, b1);
            u32x4 w; w[0] = a0; w[1] = a1; w[2] = b0; w[3] = b1;
            bf16x8 ea = __builtin_bit_cast(bf16x8, w);
            bf16x8 x0 = *(const bf16x8*)(xb0 + j0 + grp * 16);
            bf16x8 x1 = *(const bf16x8*)(xb1 + j0 + grp * 16);
            p0 = __builtin_amdgcn_mfma_f32_32x32x16_bf16(ea, x0, p0, 0, 0, 0);
            p1 = __builtin_amdgcn_mfma_f32_32x32x16_bf16(ea, x1, p1, 0, 0, 0);
        }
    }
    smr += __shfl_xor(smr, 32, 64);
    if (lane < 32) redsum[wv][l31] = smr;
    #pragma unroll
    for (int reg = 0; reg < 16; reg++) {
        int row = (reg & 3) + 8 * (reg >> 2) + 4 * hi;
        red_pv[wv][row][l31]      = p0[reg];
        red_pv[wv][row][32 + l31] = p1[reg];
    }
    __syncthreads();

    for (int i = tid; i < RT * 64; i += 256) {
        int r = i >> 6, d = i & 63;
        int grow = row0 + r;
        if (grow < LL) {
            float sum = redsum[0][r] + redsum[1][r] + redsum[2][r] + redsum[3][r];
            float o = (red_pv[0][r][d] + red_pv[1][r][d]) + (red_pv[2][r][d] + red_pv[3][r][d]);
            size_t gi = ((size_t)b * LL + grow) * 64 + d;
            Z[gi] = o * (1.0f / sum) + Xn[gi];
        }
    }
}

// ---------------- Kernel 3: fused LN + FFN + residual ----------------
__global__ __launch_bounds__(256) void k_ffn(
    const float* __restrict__ Zb, const float* __restrict__ fg, const float* __restrict__ fb,
    const float* __restrict__ w1, const float* __restrict__ b1,
    const float* __restrict__ w2, const float* __restrict__ b2,
    float* __restrict__ out)
{
    const int G2 = 16;
    __shared__ float zr[G2][64];
    __shared__ float zl[G2][64];
    __shared__ float h[G2][DHID];
    int tid = threadIdx.x;
    int w = tid >> 6, lane = tid & 63;
    size_t row0 = (size_t)blockIdx.x * G2;
    for (int rr = w; rr < G2; rr += 4) {
        float zv = Zb[(row0 + rr) * 64 + lane];
        zr[rr][lane] = zv;
        float m = zv;
        #pragma unroll
        for (int o = 32; o; o >>= 1) m += __shfl_xor(m, o, 64);
        m *= (1.0f / 64.0f);
        float dv = zv - m;
        float var = dv * dv;
        #pragma unroll
        for (int o = 32; o; o >>= 1) var += __shfl_xor(var, o, 64);
        var *= (1.0f / 64.0f);
        zl[rr][lane] = dv * (1.0f / sqrtf(var + LNEPS)) * fg[lane] + fb[lane];
    }
    __syncthreads();
    float hacc[G2];
    #pragma unroll
    for (int g = 0; g < G2; g++) hacc[g] = 0.f;
    for (int d = 0; d < 64; d++) {
        float wv1 = w1[d * DHID + tid];
        #pragma unroll
        for (int g = 0; g < G2; g++) hacc[g] += zl[g][d] * wv1;
    }
    float b1v = b1[tid];
    #pragma unroll
    for (int g = 0; g < G2; g++) h[g][tid] = fmaxf(hacc[g] + b1v, 0.f);
    __syncthreads();
    float oacc[4] = {0.f, 0.f, 0.f, 0.f};
    for (int i = 0; i < DHID; i++) {
        float wv2 = w2[i * 64 + lane];
        #pragma unroll
        for (int rr = 0; rr < 4; rr++) oacc[rr] += h[w * 4 + rr][i] * wv2;
    }
    float b2v = b2[lane];
    #pragma unroll
    for (int rr = 0; rr < 4; rr++)
        out[(row0 + w * 4 + rr) * 64 + lane] = zr[w * 4 + rr][lane] + oacc[rr] + b2v;
}

extern "C" void kernel_launch(void* const* d_in, const int* in_sizes, int n_in,
                              void* d_out, int out_size, void* d_ws, size_t ws_size,
                              hipStream_t stream)
{
    const float* x      = (const float*)d_in[0];
    const float* stg    = (const float*)d_in[1];
    const float* Wq     = (const float*)d_in[2];
    const float* bq     = (const float*)d_in[3];
    const float* Wk     = (const float*)d_in[4];
    const float* bk     = (const float*)d_in[5];
    const float* gamma  = (const float*)d_in[6];
    const float* beta   = (const float*)d_in[7];
    const float* fgamma = (const float*)d_in[8];
    const float* fbeta  = (const float*)d_in[9];
    const float* w1     = (const float*)d_in[10];
    const float* b1     = (const float*)d_in[11];
    const float* w2     = (const float*)d_in[12];
    const float* b2     = (const float*)d_in[13];
    const int*   topk   = (const int*)d_in[14];
    float* out = (float*)d_out;

    const size_t rows  = (size_t)NBATCH * LL;    // 19872
    const size_t prows = (size_t)NBATCH * LLP;   // 19968
    float* Xn = (float*)d_ws;                    // rows*64 f32
    float* Qb = Xn + rows * 64;                  // prows*64 f32 (padded)
    float* Z  = Qb + prows * 64;                 // rows*64 f32
    short* Kbf  = (short*)(Z + rows * 64);       // prows*64 bf16
    short* XbfT = Kbf + prows * 64;              // prows*64 bf16 (transposed layout)
    unsigned* TG = (unsigned*)(XbfT + prows * 64); // prows u32
    // total ~19.6 MB — well inside the proven ws budget

    k_lnproj<<<(int)(rows / 4), 256, 0, stream>>>(x, Wq, bq, Wk, bk, gamma, beta, Xn, Qb, Kbf);
    k_prep<<<NBATCH * 39, 256, 0, stream>>>(Xn, XbfT, Kbf, Qb);
    k_score<<<NBATCH * TILES, 256, 0, stream>>>(Qb, Kbf, stg, topk, TG);
    k_pv<<<NBATCH * TILES, 256, 0, stream>>>(Xn, Qb, Kbf, XbfT, stg, TG, Z);
    k_ffn<<<(int)(rows / 16), 256, 0, stream>>>(Z, fgamma, fbeta, w1, b1, w2, b2, out);
}

// Round 8
// 384.617 us; speedup vs baseline: 1.1284x; 1.1284x over previous
//
#include <hip/hip_runtime.h>

#define NBATCH 8
#define NN     207
#define DHID   256
#define LL     2484      // 12*207
#define LLP    2496      // padded to multiple of 32
#define RT     32        // rows per block in score & pv kernels
#define TILES  78        // LLP/32
#define LNEPS  1e-5f

typedef __attribute__((ext_vector_type(8)))  short bf16x8;
typedef __attribute__((ext_vector_type(4)))  unsigned u32x4;
typedef __attribute__((ext_vector_type(16))) float f32x16;

__device__ __forceinline__ short f2bf(float f) {
    unsigned u = __float_as_uint(f);
    unsigned r = (u + 0x7FFFu + ((u >> 16) & 1u)) >> 16;
    return (short)r;
}
__device__ __forceinline__ unsigned cvt_pk_bf16(float lo, float hi) {
    unsigned r;
    asm("v_cvt_pk_bf16_f32 %0, %1, %2" : "=v"(r) : "v"(lo), "v"(hi));
    return r;
}
__device__ __forceinline__ void pl32swap(unsigned& a, unsigned& b) {
    asm("v_permlane32_swap_b32 %0, %1" : "+v"(a), "+v"(b));
}

// ---------------- Kernel 1: LayerNorm + Q/K projections ----------------
__global__ __launch_bounds__(256) void k_lnproj(
    const float* __restrict__ x, const float* __restrict__ Wq, const float* __restrict__ bq,
    const float* __restrict__ Wk, const float* __restrict__ bk,
    const float* __restrict__ gamma, const float* __restrict__ beta,
    float* __restrict__ Xn, float* __restrict__ Qb, short* __restrict__ Kbf)
{
    __shared__ float xrow[4][64];
    int w = threadIdx.x >> 6, lane = threadIdx.x & 63;
    size_t row = (size_t)blockIdx.x * 4 + w;
    float xv = x[row * 64 + lane];
    float m = xv;
    #pragma unroll
    for (int o = 32; o; o >>= 1) m += __shfl_xor(m, o, 64);
    m *= (1.0f / 64.0f);
    float dv = xv - m;
    float var = dv * dv;
    #pragma unroll
    for (int o = 32; o; o >>= 1) var += __shfl_xor(var, o, 64);
    var *= (1.0f / 64.0f);
    float xg = dv * (1.0f / sqrtf(var + LNEPS)) * gamma[lane] + beta[lane];
    Xn[row * 64 + lane] = xg;
    xrow[w][lane] = xg;
    __syncthreads();
    float q = bq[lane], k = bk[lane];
    #pragma unroll 8
    for (int e = 0; e < 64; e++) {
        float xe = xrow[w][e];
        q += xe * Wq[e * 64 + lane];
        k += xe * Wk[e * 64 + lane];
    }
    int br = (int)(row / LL);
    int jl = (int)(row - (size_t)br * LL);
    Qb[((size_t)br * LLP + jl) * 64 + lane] = q;
    Kbf[((size_t)br * LLP + jl) * 64 + lane] = f2bf(k);
}

// ---------------- Kernel 1b: transpose Xn -> bf16 X^T, zero all pads ----------------
__global__ __launch_bounds__(256) void k_prep(
    const float* __restrict__ Xn, short* __restrict__ XbfT,
    short* __restrict__ Kbf, float* __restrict__ Qb)
{
    __shared__ float tile[64][65];
    int bb = blockIdx.x & 7;
    int jt = blockIdx.x >> 3;          // 0..38
    int j0 = jt * 64;
    for (int i = threadIdx.x; i < 4096; i += 256) {
        int jl = i >> 6, d = i & 63;
        int j = j0 + jl;
        tile[jl][d] = (j < LL) ? Xn[((size_t)bb * LL + j) * 64 + d] : 0.f;
    }
    __syncthreads();
    for (int i = threadIdx.x; i < 4096; i += 256) {
        int d = i >> 6, jl = i & 63;
        XbfT[((size_t)bb * 64 + d) * LLP + j0 + jl] = f2bf(tile[jl][d]);
    }
    if (jt == 38) {
        for (int i = threadIdx.x; i < (LLP - LL) * 64; i += 256) {
            int jl = i >> 6, d = i & 63;
            Kbf[((size_t)bb * LLP + LL + jl) * 64 + d] = 0;
            Qb [((size_t)bb * LLP + LL + jl) * 64 + d] = 0.f;
        }
    }
}

// --------------- suffix-scan select ---------------
__device__ __forceinline__ int scan_select(const unsigned* __restrict__ h, int lane, unsigned& kr)
{
    unsigned c0 = h[lane * 4 + 0];
    unsigned c1 = h[lane * 4 + 1];
    unsigned c2 = h[lane * 4 + 2];
    unsigned c3 = h[lane * 4 + 3];
    unsigned S = c0 + c1 + c2 + c3;
    unsigned T = S;
    #pragma unroll
    for (int off = 1; off < 64; off <<= 1) {
        unsigned t = __shfl_down(T, off, 64);
        T += (lane + off < 64) ? t : 0u;
    }
    unsigned Tn = T - S;
    unsigned sfx3 = c3 + Tn, sfx2 = c2 + sfx3, sfx1 = c1 + sfx2, sfx0 = c0 + sfx1;
    int hit = -1; unsigned nk = 0u;
    if (sfx3 >= kr && Tn   < kr) { hit = lane * 4 + 3; nk = kr - Tn; }
    if (sfx2 >= kr && sfx3 < kr) { hit = lane * 4 + 2; nk = kr - sfx3; }
    if (sfx1 >= kr && sfx2 < kr) { hit = lane * 4 + 1; nk = kr - sfx2; }
    if (sfx0 >= kr && sfx1 < kr) { hit = lane * 4 + 0; nk = kr - sfx1; }
    unsigned long long mask = __ballot(hit >= 0);
    int src = __ffsll((unsigned long long)mask) - 1;
    int bin = __shfl(hit, src, 64);
    kr = (unsigned)__shfl((int)nk, src, 64);
    return bin;
}

// ---------------- Kernel 2a: swapped-MFMA scores (2 sweeps) -> top-k threshold ----------------
// Each lane owns ONE query row (lane-per-row, same structure as k_pv).
__global__ __launch_bounds__(256, 2) void k_score(
    const float* __restrict__ Qb, const short* __restrict__ Kbf,
    const float* __restrict__ stg, const int* __restrict__ topk_p,
    unsigned* __restrict__ TG)
{
    __shared__ unsigned hist[RT * 256];     // 32 KB
    __shared__ int gmax_lds[RT];
    __shared__ int b0_lds[RT];
    __shared__ int kr_lds[RT];
    __shared__ int thr_lds[RT];

    int tid = threadIdx.x;
    int lane = tid & 63, wv = tid >> 6;
    int hi = lane >> 5, l31 = lane & 31;
    int b = blockIdx.x & 7;
    int tile = blockIdx.x >> 3;             // 0..77
    int row0 = tile * RT;

    for (int i = tid; i < RT * 256; i += 256) hist[i] = 0u;
    if (tid < RT) gmax_lds[tid] = 0;

    int keff;
    { int tk = *topk_p; keff = (tk < 5) ? tk * NN : tk; }

    // B-operand: this lane's own query row (padded Qb -> always in-bounds)
    bf16x8 qf[4];
    {
        const float* qp = Qb + ((size_t)b * LLP + row0 + l31) * 64 + hi * 8;
        #pragma unroll
        for (int kk = 0; kk < 4; kk++) {
            bf16x8 f;
            #pragma unroll
            for (int e = 0; e < 8; e++) f[e] = f2bf(qp[kk * 16 + e]);
            qf[kk] = f;
        }
    }
    int query = row0 + l31;
    bool rv = (query < LL);
    const float* stgrow = stg + (size_t)b * LL * LL + (size_t)query * LL;

    int kt0 = wv * 20;
    int kt1 = (kt0 + 20 < TILES) ? kt0 + 20 : TILES;
    __syncthreads();   // hist zeros + gmax init visible

    // ---- sweep 1: g -> coarse hist + per-lane gmax ----
    int gmx = 0;
    for (int kt = kt0; kt < kt1; ++kt) {
        int j0 = kt * 32;
        const short* kbase = Kbf + ((size_t)b * LLP + j0 + l31) * 64 + hi * 8;
        bf16x8 kv0 = *(const bf16x8*)(kbase);
        bf16x8 kv1 = *(const bf16x8*)(kbase + 16);
        bf16x8 kv2 = *(const bf16x8*)(kbase + 32);
        bf16x8 kv3 = *(const bf16x8*)(kbase + 48);
        int jbA = j0 + 4 * hi;          // grp0 quad 1
        int jbB = jbA + 8;              // grp0 quad 2
        int jbC = j0 + 16 + 4 * hi;     // grp1 quad 1
        int jbD = jbC + 8;              // grp1 quad 2
        float4 z4 = make_float4(0.f, 0.f, 0.f, 0.f);
        float4 sA = (rv && jbA < LL) ? *(const float4*)(stgrow + jbA) : z4;
        float4 sB = (rv && jbB < LL) ? *(const float4*)(stgrow + jbB) : z4;
        float4 sC = (rv && jbC < LL) ? *(const float4*)(stgrow + jbC) : z4;
        float4 sD = (rv && jbD < LL) ? *(const float4*)(stgrow + jbD) : z4;
        f32x16 c = {0.f,0.f,0.f,0.f,0.f,0.f,0.f,0.f,0.f,0.f,0.f,0.f,0.f,0.f,0.f,0.f};
        c = __builtin_amdgcn_mfma_f32_32x32x16_bf16(kv0, qf[0], c, 0, 0, 0);
        c = __builtin_amdgcn_mfma_f32_32x32x16_bf16(kv1, qf[1], c, 0, 0, 0);
        c = __builtin_amdgcn_mfma_f32_32x32x16_bf16(kv2, qf[2], c, 0, 0, 0);
        c = __builtin_amdgcn_mfma_f32_32x32x16_bf16(kv3, qf[3], c, 0, 0, 0);
        bool vA = rv && (jbA < LL), vB = rv && (jbB < LL);
        bool vC = rv && (jbC < LL), vD = rv && (jbD < LL);
        float svs[16] = {sA.x, sA.y, sA.z, sA.w, sB.x, sB.y, sB.z, sB.w,
                         sC.x, sC.y, sC.z, sC.w, sD.x, sD.y, sD.z, sD.w};
        #pragma unroll
        for (int r = 0; r < 16; r++) {
            bool v = (r < 4) ? vA : (r < 8) ? vB : (r < 12) ? vC : vD;
            float sg = 1.0f / (1.0f + __expf(c[r] * -0.125f));
            float s = sg * svs[r];
            int g = (int)(s * 65536.0f); g = (g > 65535) ? 65535 : g;
            if (v) {
                atomicAdd(&hist[l31 * 256 + (g >> 8)], 1u);
                gmx = (g > gmx) ? g : gmx;
            }
        }
    }
    {
        int o2 = __shfl_xor(gmx, 32, 64);
        gmx = (o2 > gmx) ? o2 : gmx;
        if (lane < 32) atomicMax(&gmax_lds[l31], gmx);
    }
    __syncthreads();

    // pass-0 scan: 8 rows per wave
    #pragma unroll 1
    for (int rr = 0; rr < 8; rr++) {
        int row = wv * 8 + rr;
        unsigned kr = (unsigned)keff;
        int bin = scan_select(&hist[row * 256], lane, kr);
        if (lane == 0) { b0_lds[row] = bin; kr_lds[row] = (int)kr; }
    }
    __syncthreads();
    for (int i = tid; i < RT * 256; i += 256) hist[i] = 0u;
    __syncthreads();

    // ---- sweep 2: recompute g (bitwise identical), refine within coarse bin ----
    int b0 = b0_lds[l31];
    for (int kt = kt0; kt < kt1; ++kt) {
        int j0 = kt * 32;
        const short* kbase = Kbf + ((size_t)b * LLP + j0 + l31) * 64 + hi * 8;
        bf16x8 kv0 = *(const bf16x8*)(kbase);
        bf16x8 kv1 = *(const bf16x8*)(kbase + 16);
        bf16x8 kv2 = *(const bf16x8*)(kbase + 32);
        bf16x8 kv3 = *(const bf16x8*)(kbase + 48);
        int jbA = j0 + 4 * hi;
        int jbB = jbA + 8;
        int jbC = j0 + 16 + 4 * hi;
        int jbD = jbC + 8;
        float4 z4 = make_float4(0.f, 0.f, 0.f, 0.f);
        float4 sA = (rv && jbA < LL) ? *(const float4*)(stgrow + jbA) : z4;
        float4 sB = (rv && jbB < LL) ? *(const float4*)(stgrow + jbB) : z4;
        float4 sC = (rv && jbC < LL) ? *(const float4*)(stgrow + jbC) : z4;
        float4 sD = (rv && jbD < LL) ? *(const float4*)(stgrow + jbD) : z4;
        f32x16 c = {0.f,0.f,0.f,0.f,0.f,0.f,0.f,0.f,0.f,0.f,0.f,0.f,0.f,0.f,0.f,0.f};
        c = __builtin_amdgcn_mfma_f32_32x32x16_bf16(kv0, qf[0], c, 0, 0, 0);
        c = __builtin_amdgcn_mfma_f32_32x32x16_bf16(kv1, qf[1], c, 0, 0, 0);
        c = __builtin_amdgcn_mfma_f32_32x32x16_bf16(kv2, qf[2], c, 0, 0, 0);
        c = __builtin_amdgcn_mfma_f32_32x32x16_bf16(kv3, qf[3], c, 0, 0, 0);
        bool vA = rv && (jbA < LL), vB = rv && (jbB < LL);
        bool vC = rv && (jbC < LL), vD = rv && (jbD < LL);
        float svs[16] = {sA.x, sA.y, sA.z, sA.w, sB.x, sB.y, sB.z, sB.w,
                         sC.x, sC.y, sC.z, sC.w, sD.x, sD.y, sD.z, sD.w};
        #pragma unroll
        for (int r = 0; r < 16; r++) {
            bool v = (r < 4) ? vA : (r < 8) ? vB : (r < 12) ? vC : vD;
            float sg = 1.0f / (1.0f + __expf(c[r] * -0.125f));
            float s = sg * svs[r];
            int g = (int)(s * 65536.0f); g = (g > 65535) ? 65535 : g;
            if (v && (g >> 8) == b0) atomicAdd(&hist[l31 * 256 + (g & 255)], 1u);
        }
    }
    __syncthreads();
    #pragma unroll 1
    for (int rr = 0; rr < 8; rr++) {
        int row = wv * 8 + rr;
        unsigned kr = (unsigned)kr_lds[row];
        int bin = scan_select(&hist[row * 256], lane, kr);
        if (lane == 0) thr_lds[row] = b0_lds[row] * 256 + bin;
    }
    __syncthreads();

    if (tid < RT) {
        int grow = row0 + tid;
        unsigned tg = (grow < LL)
            ? (((unsigned)gmax_lds[tid] << 16) | (unsigned)(thr_lds[tid] & 0xFFFF))
            : 0xFFFFFFFFu;
        TG[(size_t)b * LLP + grow] = tg;
    }
}

// ---------------- Kernel 2b: PV with swapped-QK recompute + permlane pack ----------------
__global__ __launch_bounds__(256, 4) void k_pv(
    const float* __restrict__ Xn, const float* __restrict__ Qb,
    const short* __restrict__ Kbf, const short* __restrict__ XbfT,
    const float* __restrict__ stg, const unsigned* __restrict__ TG,
    float* __restrict__ Z)
{
    __shared__ float red_pv[4][RT][64];     // 32 KB
    __shared__ float redsum[4][RT];

    int tid = threadIdx.x;
    int lane = tid & 63, wv = tid >> 6;
    int hi = lane >> 5, l31 = lane & 31;
    int b = blockIdx.x & 7;
    int tile = blockIdx.x >> 3;
    int row0 = tile * RT;

    // B-operand: this lane's own query row (padded Qb)
    bf16x8 qf[4];
    {
        const float* qp = Qb + ((size_t)b * LLP + row0 + l31) * 64 + hi * 8;
        #pragma unroll
        for (int kk = 0; kk < 4; kk++) {
            bf16x8 f;
            #pragma unroll
            for (int e = 0; e < 8; e++) f[e] = f2bf(qp[kk * 16 + e]);
            qf[kk] = f;
        }
    }
    unsigned tg = TG[(size_t)b * LLP + row0 + l31];
    int thr = (int)(tg & 0xFFFFu);
    int gmax = (int)(tg >> 16);
    int query = row0 + l31;
    bool rv = (query < LL);
    const float* stgrow = stg + (size_t)b * LL * LL + (size_t)query * LL;
    const short* xb0 = XbfT + ((size_t)b * 64 + l31) * LLP + hi * 8;
    const short* xb1 = XbfT + ((size_t)b * 64 + 32 + l31) * LLP + hi * 8;

    f32x16 p0 = {0.f,0.f,0.f,0.f,0.f,0.f,0.f,0.f,0.f,0.f,0.f,0.f,0.f,0.f,0.f,0.f};
    f32x16 p1 = p0;
    float smr = 0.f;

    int kt0 = wv * 20;
    int kt1 = (kt0 + 20 < TILES) ? kt0 + 20 : TILES;
    for (int kt = kt0; kt < kt1; ++kt) {
        int j0 = kt * 32;
        // swapped QK^T: A = K (rows j), B = Q (cols = query) -> lane holds its row's scores
        f32x16 c = {0.f,0.f,0.f,0.f,0.f,0.f,0.f,0.f,0.f,0.f,0.f,0.f,0.f,0.f,0.f,0.f};
        const short* kbase = Kbf + ((size_t)b * LLP + j0 + l31) * 64 + hi * 8;
        #pragma unroll
        for (int kk = 0; kk < 4; kk++) {
            bf16x8 kv = *(const bf16x8*)(kbase + kk * 16);
            c = __builtin_amdgcn_mfma_f32_32x32x16_bf16(kv, qf[kk], c, 0, 0, 0);
        }
        #pragma unroll
        for (int grp = 0; grp < 2; grp++) {
            int jb1 = j0 + grp * 16 + 4 * hi;
            int jb2 = jb1 + 8;
            float4 s1 = (rv && jb1 + 3 < LL) ? *(const float4*)(stgrow + jb1)
                                             : make_float4(0.f, 0.f, 0.f, 0.f);
            float4 s2 = (rv && jb2 + 3 < LL) ? *(const float4*)(stgrow + jb2)
                                             : make_float4(0.f, 0.f, 0.f, 0.f);
            float sv[8] = {s1.x, s1.y, s1.z, s1.w, s2.x, s2.y, s2.z, s2.w};
            float ev[8];
            #pragma unroll
            for (int r = 0; r < 8; r++) {
                float sg = 1.0f / (1.0f + __expf(c[grp * 8 + r] * -0.125f));
                float s = sg * sv[r];
                int g = (int)(s * 65536.0f); g = (g > 65535) ? 65535 : g;
                bool keep = (g > thr) || (g == gmax && sv[r] > 0.f);
                ev[r] = keep ? __expf((float)(g - gmax) * (1.0f / 65536.0f)) : 0.f;
                smr += ev[r];
            }
            unsigned a0 = cvt_pk_bf16(ev[0], ev[1]);
            unsigned a1 = cvt_pk_bf16(ev[2], ev[3]);
            unsigned b0 = cvt_pk_bf16(ev[4], ev[5]);
            unsigned b1 = cvt_pk_bf16(ev[6], ev[7]);
            pl32swap(a0, b0);
            pl32swap(a1, b1);
            u32x4 w; w[0] = a0; w[1] = a1; w[2] = b0; w[3] = b1;
            bf16x8 ea = __builtin_bit_cast(bf16x8, w);
            bf16x8 x0 = *(const bf16x8*)(xb0 + j0 + grp * 16);
            bf16x8 x1 = *(const bf16x8*)(xb1 + j0 + grp * 16);
            p0 = __builtin_amdgcn_mfma_f32_32x32x16_bf16(ea, x0, p0, 0, 0, 0);
            p1 = __builtin_amdgcn_mfma_f32_32x32x16_bf16(ea, x1, p1, 0, 0, 0);
        }
    }
    smr += __shfl_xor(smr, 32, 64);
    if (lane < 32) redsum[wv][l31] = smr;
    #pragma unroll
    for (int reg = 0; reg < 16; reg++) {
        int row = (reg & 3) + 8 * (reg >> 2) + 4 * hi;
        red_pv[wv][row][l31]      = p0[reg];
        red_pv[wv][row][32 + l31] = p1[reg];
    }
    __syncthreads();

    for (int i = tid; i < RT * 64; i += 256) {
        int r = i >> 6, d = i & 63;
        int grow = row0 + r;
        if (grow < LL) {
            float sum = redsum[0][r] + redsum[1][r] + redsum[2][r] + redsum[3][r];
            float o = (red_pv[0][r][d] + red_pv[1][r][d]) + (red_pv[2][r][d] + red_pv[3][r][d]);
            size_t gi = ((size_t)b * LL + grow) * 64 + d;
            Z[gi] = o * (1.0f / sum) + Xn[gi];
        }
    }
}

// ---------------- Kernel 3: fused LN + FFN + residual ----------------
__global__ __launch_bounds__(256) void k_ffn(
    const float* __restrict__ Zb, const float* __restrict__ fg, const float* __restrict__ fb,
    const float* __restrict__ w1, const float* __restrict__ b1,
    const float* __restrict__ w2, const float* __restrict__ b2,
    float* __restrict__ out)
{
    const int G2 = 16;
    __shared__ float zr[G2][64];
    __shared__ float zl[G2][64];
    __shared__ float h[G2][DHID];
    int tid = threadIdx.x;
    int w = tid >> 6, lane = tid & 63;
    size_t row0 = (size_t)blockIdx.x * G2;
    for (int rr = w; rr < G2; rr += 4) {
        float zv = Zb[(row0 + rr) * 64 + lane];
        zr[rr][lane] = zv;
        float m = zv;
        #pragma unroll
        for (int o = 32; o; o >>= 1) m += __shfl_xor(m, o, 64);
        m *= (1.0f / 64.0f);
        float dv = zv - m;
        float var = dv * dv;
        #pragma unroll
        for (int o = 32; o; o >>= 1) var += __shfl_xor(var, o, 64);
        var *= (1.0f / 64.0f);
        zl[rr][lane] = dv * (1.0f / sqrtf(var + LNEPS)) * fg[lane] + fb[lane];
    }
    __syncthreads();
    float hacc[G2];
    #pragma unroll
    for (int g = 0; g < G2; g++) hacc[g] = 0.f;
    for (int d = 0; d < 64; d++) {
        float wv1 = w1[d * DHID + tid];
        #pragma unroll
        for (int g = 0; g < G2; g++) hacc[g] += zl[g][d] * wv1;
    }
    float b1v = b1[tid];
    #pragma unroll
    for (int g = 0; g < G2; g++) h[g][tid] = fmaxf(hacc[g] + b1v, 0.f);
    __syncthreads();
    float oacc[4] = {0.f, 0.f, 0.f, 0.f};
    for (int i = 0; i < DHID; i++) {
        float wv2 = w2[i * 64 + lane];
        #pragma unroll
        for (int rr = 0; rr < 4; rr++) oacc[rr] += h[w * 4 + rr][i] * wv2;
    }
    float b2v = b2[lane];
    #pragma unroll
    for (int rr = 0; rr < 4; rr++)
        out[(row0 + w * 4 + rr) * 64 + lane] = zr[w * 4 + rr][lane] + oacc[rr] + b2v;
}

extern "C" void kernel_launch(void* const* d_in, const int* in_sizes, int n_in,
                              void* d_out, int out_size, void* d_ws, size_t ws_size,
                              hipStream_t stream)
{
    const float* x      = (const float*)d_in[0];
    const float* stg    = (const float*)d_in[1];
    const float* Wq     = (const float*)d_in[2];
    const float* bq     = (const float*)d_in[3];
    const float* Wk     = (const float*)d_in[4];
    const float* bk     = (const float*)d_in[5];
    const float* gamma  = (const float*)d_in[6];
    const float* beta   = (const float*)d_in[7];
    const float* fgamma = (const float*)d_in[8];
    const float* fbeta  = (const float*)d_in[9];
    const float* w1     = (const float*)d_in[10];
    const float* b1     = (const float*)d_in[11];
    const float* w2     = (const float*)d_in[12];
    const float* b2     = (const float*)d_in[13];
    const int*   topk   = (const int*)d_in[14];
    float* out = (float*)d_out;

    const size_t rows  = (size_t)NBATCH * LL;    // 19872
    const size_t prows = (size_t)NBATCH * LLP;   // 19968
    float* Xn = (float*)d_ws;                    // rows*64 f32
    float* Qb = Xn + rows * 64;                  // prows*64 f32 (padded)
    float* Z  = Qb + prows * 64;                 // rows*64 f32
    short* Kbf  = (short*)(Z + rows * 64);       // prows*64 bf16
    short* XbfT = Kbf + prows * 64;              // prows*64 bf16 (transposed layout)
    unsigned* TG = (unsigned*)(XbfT + prows * 64); // prows u32
    // total ~19.6 MB — well inside the proven ws budget

    k_lnproj<<<(int)(rows / 4), 256, 0, stream>>>(x, Wq, bq, Wk, bk, gamma, beta, Xn, Qb, Kbf);
    k_prep<<<NBATCH * 39, 256, 0, stream>>>(Xn, XbfT, Kbf, Qb);
    k_score<<<NBATCH * TILES, 256, 0, stream>>>(Qb, Kbf, stg, topk, TG);
    k_pv<<<NBATCH * TILES, 256, 0, stream>>>(Xn, Qb, Kbf, XbfT, stg, TG, Z);
    k_ffn<<<(int)(rows / 16), 256, 0, stream>>>(Z, fgamma, fbeta, w1, b1, w2, b2, out);
}

// Round 9
// 308.607 us; speedup vs baseline: 1.4063x; 1.2463x over previous
//
#include <hip/hip_runtime.h>

#define NBATCH 8
#define NN     207
#define DHID   256
#define LL     2484      // 12*207
#define LLP    2496      // padded to multiple of 32
#define RT     32        // query rows per block
#define TILES  78        // LLP/32
#define TPW    10        // j-tiles per wave (8 waves)
#define LNEPS  1e-5f

typedef __attribute__((ext_vector_type(8)))  short bf16x8;
typedef __attribute__((ext_vector_type(4)))  unsigned u32x4;
typedef __attribute__((ext_vector_type(16))) float f32x16;

__device__ __forceinline__ short f2bf(float f) {
    unsigned u = __float_as_uint(f);
    unsigned r = (u + 0x7FFFu + ((u >> 16) & 1u)) >> 16;
    return (short)r;
}
__device__ __forceinline__ unsigned cvt_pk_bf16(float lo, float hi) {
    unsigned r;
    asm("v_cvt_pk_bf16_f32 %0, %1, %2" : "=v"(r) : "v"(lo), "v"(hi));
    return r;
}
__device__ __forceinline__ void pl32swap(unsigned& a, unsigned& b) {
    asm("v_permlane32_swap_b32 %0, %1" : "+v"(a), "+v"(b));
}

// ---------------- Kernel 1: LayerNorm + Q/K projections ----------------
__global__ __launch_bounds__(256) void k_lnproj(
    const float* __restrict__ x, const float* __restrict__ Wq, const float* __restrict__ bq,
    const float* __restrict__ Wk, const float* __restrict__ bk,
    const float* __restrict__ gamma, const float* __restrict__ beta,
    float* __restrict__ Xn, float* __restrict__ Qb, short* __restrict__ Kbf)
{
    __shared__ float xrow[4][64];
    int w = threadIdx.x >> 6, lane = threadIdx.x & 63;
    size_t row = (size_t)blockIdx.x * 4 + w;
    float xv = x[row * 64 + lane];
    float m = xv;
    #pragma unroll
    for (int o = 32; o; o >>= 1) m += __shfl_xor(m, o, 64);
    m *= (1.0f / 64.0f);
    float dv = xv - m;
    float var = dv * dv;
    #pragma unroll
    for (int o = 32; o; o >>= 1) var += __shfl_xor(var, o, 64);
    var *= (1.0f / 64.0f);
    float xg = dv * (1.0f / sqrtf(var + LNEPS)) * gamma[lane] + beta[lane];
    Xn[row * 64 + lane] = xg;
    xrow[w][lane] = xg;
    __syncthreads();
    float q = bq[lane], k = bk[lane];
    #pragma unroll 8
    for (int e = 0; e < 64; e++) {
        float xe = xrow[w][e];
        q += xe * Wq[e * 64 + lane];
        k += xe * Wk[e * 64 + lane];
    }
    int br = (int)(row / LL);
    int jl = (int)(row - (size_t)br * LL);
    Qb[((size_t)br * LLP + jl) * 64 + lane] = q;
    Kbf[((size_t)br * LLP + jl) * 64 + lane] = f2bf(k);
}

// ---------------- Kernel 1b: transpose Xn -> bf16 X^T, zero all pads ----------------
__global__ __launch_bounds__(256) void k_prep(
    const float* __restrict__ Xn, short* __restrict__ XbfT,
    short* __restrict__ Kbf, float* __restrict__ Qb)
{
    __shared__ float tile[64][65];
    int bb = blockIdx.x & 7;
    int jt = blockIdx.x >> 3;          // 0..38
    int j0 = jt * 64;
    for (int i = threadIdx.x; i < 4096; i += 256) {
        int jl = i >> 6, d = i & 63;
        int j = j0 + jl;
        tile[jl][d] = (j < LL) ? Xn[((size_t)bb * LL + j) * 64 + d] : 0.f;
    }
    __syncthreads();
    for (int i = threadIdx.x; i < 4096; i += 256) {
        int d = i >> 6, jl = i & 63;
        XbfT[((size_t)bb * 64 + d) * LLP + j0 + jl] = f2bf(tile[jl][d]);
    }
    if (jt == 38) {
        for (int i = threadIdx.x; i < (LLP - LL) * 64; i += 256) {
            int jl = i >> 6, d = i & 63;
            Kbf[((size_t)bb * LLP + LL + jl) * 64 + d] = 0;
            Qb [((size_t)bb * LLP + LL + jl) * 64 + d] = 0.f;
        }
    }
}

// --------------- suffix-scan select ---------------
__device__ __forceinline__ int scan_select(const unsigned* __restrict__ h, int lane, unsigned& kr)
{
    unsigned c0 = h[lane * 4 + 0];
    unsigned c1 = h[lane * 4 + 1];
    unsigned c2 = h[lane * 4 + 2];
    unsigned c3 = h[lane * 4 + 3];
    unsigned S = c0 + c1 + c2 + c3;
    unsigned T = S;
    #pragma unroll
    for (int off = 1; off < 64; off <<= 1) {
        unsigned t = __shfl_down(T, off, 64);
        T += (lane + off < 64) ? t : 0u;
    }
    unsigned Tn = T - S;
    unsigned sfx3 = c3 + Tn, sfx2 = c2 + sfx3, sfx1 = c1 + sfx2, sfx0 = c0 + sfx1;
    int hit = -1; unsigned nk = 0u;
    if (sfx3 >= kr && Tn   < kr) { hit = lane * 4 + 3; nk = kr - Tn; }
    if (sfx2 >= kr && sfx3 < kr) { hit = lane * 4 + 2; nk = kr - sfx3; }
    if (sfx1 >= kr && sfx2 < kr) { hit = lane * 4 + 1; nk = kr - sfx2; }
    if (sfx0 >= kr && sfx1 < kr) { hit = lane * 4 + 0; nk = kr - sfx1; }
    unsigned long long mask = __ballot(hit >= 0);
    int src = __ffsll((unsigned long long)mask) - 1;
    int bin = __shfl(hit, src, 64);
    kr = (unsigned)__shfl((int)nk, src, 64);
    return bin;
}

// ---------------- Kernel 2: fully fused scores+select+softmax+PV, g in registers ----------------
__global__ __launch_bounds__(512, 2) void k_fused(
    const float* __restrict__ Xn, const float* __restrict__ Qb,
    const short* __restrict__ Kbf, const short* __restrict__ XbfT,
    const float* __restrict__ stg, const int* __restrict__ topk_p,
    float* __restrict__ Z)
{
    __shared__ unsigned hist[RT * 256];     // 32 KB
    __shared__ float red[RT][65];           // 8.3 KB, PV accumulation
    __shared__ float rowsum[RT];
    __shared__ int gmax_lds[RT];
    __shared__ int b0_lds[RT];
    __shared__ int kr_lds[RT];
    __shared__ int thr_lds[RT];

    int tid = threadIdx.x;
    int lane = tid & 63, wv = tid >> 6;         // wv in [0,8)
    int hi = lane >> 5, l31 = lane & 31;
    int b = blockIdx.x & 7;
    int tile = blockIdx.x >> 3;                 // 0..77
    int row0 = tile * RT;

    for (int i = tid; i < RT * 256; i += 512) hist[i] = 0u;
    for (int i = tid; i < RT * 65; i += 512) ((float*)red)[i] = 0.f;
    if (tid < RT) { rowsum[tid] = 0.f; gmax_lds[tid] = 0; }

    int keff;
    { int tk = *topk_p; keff = (tk < 5) ? tk * NN : tk; }

    // Q fragments for this lane's own query row (padded Qb -> in-bounds, zeros on pad)
    bf16x8 qf[4];
    {
        const float* qp = Qb + ((size_t)b * LLP + row0 + l31) * 64 + hi * 8;
        #pragma unroll
        for (int kk = 0; kk < 4; kk++) {
            bf16x8 f;
            #pragma unroll
            for (int e = 0; e < 8; e++) f[e] = f2bf(qp[kk * 16 + e]);
            qf[kk] = f;
        }
    }
    int query = row0 + l31;
    bool rv = (query < LL);
    const float* stgrow = stg + (size_t)b * LL * LL + (size_t)query * LL;
    __syncthreads();   // hist/red/rowsum init visible

    // ---- sweep 1: swapped-MFMA scores -> g (u16, packed in regs) + hist + gmax ----
    unsigned gpk[TPW][8];
    #pragma unroll
    for (int t = 0; t < TPW; t++)
        #pragma unroll
        for (int w2 = 0; w2 < 8; w2++) gpk[t][w2] = 0u;

    int gmx = 0;
    #pragma unroll
    for (int t = 0; t < TPW; t++) {
        int ti = wv * TPW + t;
        if (ti < TILES) {
            int j0 = ti * 32;
            const short* kbase = Kbf + ((size_t)b * LLP + j0 + l31) * 64 + hi * 8;
            bf16x8 kv0 = *(const bf16x8*)(kbase);
            bf16x8 kv1 = *(const bf16x8*)(kbase + 16);
            bf16x8 kv2 = *(const bf16x8*)(kbase + 32);
            bf16x8 kv3 = *(const bf16x8*)(kbase + 48);
            int jbA = j0 + 4 * hi;
            int jbB = jbA + 8;
            int jbC = j0 + 16 + 4 * hi;
            int jbD = jbC + 8;
            float4 z4 = make_float4(0.f, 0.f, 0.f, 0.f);
            float4 sA = (rv && jbA < LL) ? *(const float4*)(stgrow + jbA) : z4;
            float4 sB = (rv && jbB < LL) ? *(const float4*)(stgrow + jbB) : z4;
            float4 sC = (rv && jbC < LL) ? *(const float4*)(stgrow + jbC) : z4;
            float4 sD = (rv && jbD < LL) ? *(const float4*)(stgrow + jbD) : z4;
            f32x16 c = {0.f,0.f,0.f,0.f,0.f,0.f,0.f,0.f,0.f,0.f,0.f,0.f,0.f,0.f,0.f,0.f};
            c = __builtin_amdgcn_mfma_f32_32x32x16_bf16(kv0, qf[0], c, 0, 0, 0);
            c = __builtin_amdgcn_mfma_f32_32x32x16_bf16(kv1, qf[1], c, 0, 0, 0);
            c = __builtin_amdgcn_mfma_f32_32x32x16_bf16(kv2, qf[2], c, 0, 0, 0);
            c = __builtin_amdgcn_mfma_f32_32x32x16_bf16(kv3, qf[3], c, 0, 0, 0);
            bool vA = rv && (jbA < LL), vB = rv && (jbB < LL);
            bool vC = rv && (jbC < LL), vD = rv && (jbD < LL);
            float svs[16] = {sA.x, sA.y, sA.z, sA.w, sB.x, sB.y, sB.z, sB.w,
                             sC.x, sC.y, sC.z, sC.w, sD.x, sD.y, sD.z, sD.w};
            #pragma unroll
            for (int r = 0; r < 16; r++) {
                bool v = (r < 4) ? vA : (r < 8) ? vB : (r < 12) ? vC : vD;
                float sg = 1.0f / (1.0f + __expf(c[r] * -0.125f));
                float s = sg * svs[r];
                int g = (int)(s * 65536.0f); g = (g > 65535) ? 65535 : g;
                if (v) {
                    atomicAdd(&hist[l31 * 256 + (g >> 8)], 1u);
                    gmx = (g > gmx) ? g : gmx;
                } else g = 0;
                if (r & 1) gpk[t][r >> 1] |= ((unsigned)g << 16);
                else       gpk[t][r >> 1]  = (unsigned)g;
            }
        }
    }
    {
        int o2 = __shfl_xor(gmx, 32, 64);
        gmx = (o2 > gmx) ? o2 : gmx;
        if (lane < 32) atomicMax(&gmax_lds[l31], gmx);
    }
    __syncthreads();

    // ---- pass-0 scan: 4 rows per wave ----
    #pragma unroll 1
    for (int rr = 0; rr < 4; rr++) {
        int row = wv * 4 + rr;
        unsigned kr = (unsigned)keff;
        int bin = scan_select(&hist[row * 256], lane, kr);
        if (lane == 0) { b0_lds[row] = bin; kr_lds[row] = (int)kr; }
    }
    __syncthreads();
    for (int i = tid; i < RT * 256; i += 512) hist[i] = 0u;
    __syncthreads();

    // ---- sweep 2: refine from REGISTERS (no loads, no MFMA) ----
    {
        int b0c = b0_lds[l31];
        #pragma unroll
        for (int t = 0; t < TPW; t++) {
            int ti = wv * TPW + t;
            if (ti < TILES) {
                int j0 = ti * 32;
                #pragma unroll
                for (int r = 0; r < 16; r++) {
                    int j = j0 + (r & 3) + 8 * (r >> 2) + 4 * hi;
                    int g = (int)((gpk[t][r >> 1] >> ((r & 1) * 16)) & 0xFFFFu);
                    if (rv && j < LL && (g >> 8) == b0c)
                        atomicAdd(&hist[l31 * 256 + (g & 255)], 1u);
                }
            }
        }
    }
    __syncthreads();
    #pragma unroll 1
    for (int rr = 0; rr < 4; rr++) {
        int row = wv * 4 + rr;
        unsigned kr = (unsigned)kr_lds[row];
        int bin = scan_select(&hist[row * 256], lane, kr);
        if (lane == 0) thr_lds[row] = b0_lds[row] * 256 + bin;
    }
    __syncthreads();

    // ---- PV: e from registers -> bf16 fragments (cvt_pk + permlane) -> MFMA vs X^T ----
    int thr = thr_lds[l31];
    int gmax = gmax_lds[l31];
    const short* xb0 = XbfT + ((size_t)b * 64 + l31) * LLP + hi * 8;
    const short* xb1 = XbfT + ((size_t)b * 64 + 32 + l31) * LLP + hi * 8;
    f32x16 p0 = {0.f,0.f,0.f,0.f,0.f,0.f,0.f,0.f,0.f,0.f,0.f,0.f,0.f,0.f,0.f,0.f};
    f32x16 p1 = p0;
    float smr = 0.f;
    #pragma unroll
    for (int t = 0; t < TPW; t++) {
        int ti = wv * TPW + t;
        if (ti < TILES) {
            int j0 = ti * 32;
            #pragma unroll
            for (int grp = 0; grp < 2; grp++) {
                float ev[8];
                #pragma unroll
                for (int r = 0; r < 8; r++) {
                    int reg = grp * 8 + r;
                    int g = (int)((gpk[t][reg >> 1] >> ((reg & 1) * 16)) & 0xFFFFu);
                    bool keep = (g > thr) || (g == gmax && g > 0);
                    ev[r] = keep ? __expf((float)(g - gmax) * (1.0f / 65536.0f)) : 0.f;
                    smr += ev[r];
                }
                unsigned a0 = cvt_pk_bf16(ev[0], ev[1]);
                unsigned a1 = cvt_pk_bf16(ev[2], ev[3]);
                unsigned c0 = cvt_pk_bf16(ev[4], ev[5]);
                unsigned c1 = cvt_pk_bf16(ev[6], ev[7]);
                pl32swap(a0, c0);
                pl32swap(a1, c1);
                u32x4 w; w[0] = a0; w[1] = a1; w[2] = c0; w[3] = c1;
                bf16x8 ea = __builtin_bit_cast(bf16x8, w);
                bf16x8 x0 = *(const bf16x8*)(xb0 + j0 + grp * 16);
                bf16x8 x1 = *(const bf16x8*)(xb1 + j0 + grp * 16);
                p0 = __builtin_amdgcn_mfma_f32_32x32x16_bf16(ea, x0, p0, 0, 0, 0);
                p1 = __builtin_amdgcn_mfma_f32_32x32x16_bf16(ea, x1, p1, 0, 0, 0);
            }
        }
    }
    smr += __shfl_xor(smr, 32, 64);
    if (lane < 32) atomicAdd(&rowsum[l31], smr);
    #pragma unroll
    for (int reg = 0; reg < 16; reg++) {
        int row = (reg & 3) + 8 * (reg >> 2) + 4 * hi;
        atomicAdd(&red[row][l31],      p0[reg]);
        atomicAdd(&red[row][32 + l31], p1[reg]);
    }
    __syncthreads();

    for (int i = tid; i < RT * 64; i += 512) {
        int r = i >> 6, d = i & 63;
        int grow = row0 + r;
        if (grow < LL) {
            size_t gi = ((size_t)b * LL + grow) * 64 + d;
            Z[gi] = red[r][d] * (1.0f / rowsum[r]) + Xn[gi];
        }
    }
}

// ---------------- Kernel 3: fused LN + FFN + residual ----------------
__global__ __launch_bounds__(256) void k_ffn(
    const float* __restrict__ Zb, const float* __restrict__ fg, const float* __restrict__ fb,
    const float* __restrict__ w1, const float* __restrict__ b1,
    const float* __restrict__ w2, const float* __restrict__ b2,
    float* __restrict__ out)
{
    const int G2 = 16;
    __shared__ float zr[G2][64];
    __shared__ float zl[G2][64];
    __shared__ float h[G2][DHID];
    int tid = threadIdx.x;
    int w = tid >> 6, lane = tid & 63;
    size_t row0 = (size_t)blockIdx.x * G2;
    for (int rr = w; rr < G2; rr += 4) {
        float zv = Zb[(row0 + rr) * 64 + lane];
        zr[rr][lane] = zv;
        float m = zv;
        #pragma unroll
        for (int o = 32; o; o >>= 1) m += __shfl_xor(m, o, 64);
        m *= (1.0f / 64.0f);
        float dv = zv - m;
        float var = dv * dv;
        #pragma unroll
        for (int o = 32; o; o >>= 1) var += __shfl_xor(var, o, 64);
        var *= (1.0f / 64.0f);
        zl[rr][lane] = dv * (1.0f / sqrtf(var + LNEPS)) * fg[lane] + fb[lane];
    }
    __syncthreads();
    float hacc[G2];
    #pragma unroll
    for (int g = 0; g < G2; g++) hacc[g] = 0.f;
    for (int d = 0; d < 64; d++) {
        float wv1 = w1[d * DHID + tid];
        #pragma unroll
        for (int g = 0; g < G2; g++) hacc[g] += zl[g][d] * wv1;
    }
    float b1v = b1[tid];
    #pragma unroll
    for (int g = 0; g < G2; g++) h[g][tid] = fmaxf(hacc[g] + b1v, 0.f);
    __syncthreads();
    float oacc[4] = {0.f, 0.f, 0.f, 0.f};
    for (int i = 0; i < DHID; i++) {
        float wv2 = w2[i * 64 + lane];
        #pragma unroll
        for (int rr = 0; rr < 4; rr++) oacc[rr] += h[w * 4 + rr][i] * wv2;
    }
    float b2v = b2[lane];
    #pragma unroll
    for (int rr = 0; rr < 4; rr++)
        out[(row0 + w * 4 + rr) * 64 + lane] = zr[w * 4 + rr][lane] + oacc[rr] + b2v;
}

extern "C" void kernel_launch(void* const* d_in, const int* in_sizes, int n_in,
                              void* d_out, int out_size, void* d_ws, size_t ws_size,
                              hipStream_t stream)
{
    const float* x      = (const float*)d_in[0];
    const float* stg    = (const float*)d_in[1];
    const float* Wq     = (const float*)d_in[2];
    const float* bq     = (const float*)d_in[3];
    const float* Wk     = (const float*)d_in[4];
    const float* bk     = (const float*)d_in[5];
    const float* gamma  = (const float*)d_in[6];
    const float* beta   = (const float*)d_in[7];
    const float* fgamma = (const float*)d_in[8];
    const float* fbeta  = (const float*)d_in[9];
    const float* w1     = (const float*)d_in[10];
    const float* b1     = (const float*)d_in[11];
    const float* w2     = (const float*)d_in[12];
    const float* b2     = (const float*)d_in[13];
    const int*   topk   = (const int*)d_in[14];
    float* out = (float*)d_out;

    const size_t rows  = (size_t)NBATCH * LL;    // 19872
    const size_t prows = (size_t)NBATCH * LLP;   // 19968
    float* Xn = (float*)d_ws;                    // rows*64 f32
    float* Qb = Xn + rows * 64;                  // prows*64 f32 (padded)
    float* Z  = Qb + prows * 64;                 // rows*64 f32
    short* Kbf  = (short*)(Z + rows * 64);       // prows*64 bf16
    short* XbfT = Kbf + prows * 64;              // prows*64 bf16 (transposed layout)
    // total ~20.4 MB — proven ws budget

    k_lnproj<<<(int)(rows / 4), 256, 0, stream>>>(x, Wq, bq, Wk, bk, gamma, beta, Xn, Qb, Kbf);
    k_prep<<<NBATCH * 39, 256, 0, stream>>>(Xn, XbfT, Kbf, Qb);
    k_fused<<<NBATCH * TILES, 512, 0, stream>>>(Xn, Qb, Kbf, XbfT, stg, topk, Z);
    k_ffn<<<(int)(rows / 16), 256, 0, stream>>>(Z, fgamma, fbeta, w1, b1, w2, b2, out);
}